// Round 2
// baseline (70.236 us; speedup 1.0000x reference)
//
#include <hip/hip_runtime.h>
#include <hip/hip_bf16.h>
#include <stdint.h>

#define N_CLOTH     16384
#define N_OBS_VERTS 8192
#define N_OBS_FACES 16384

#define CHUNK 256                        // faces per chunk (LDS tile = 4KB)
#define NC    (N_OBS_FACES / CHUNK)      // 64 chunks
#define VPT   4                          // vertices per thread
#define TB    256                        // threads per block
#define VBLK  (N_CLOTH / (TB * VPT))     // 16 vertex-blocks -> grid 16x64 = 1024 blocks

// ---------------------------------------------------------------------------
// K1 (fused tile build + NN): each block builds its chunk's 256 prev-face
// centers in LDS (1 face/thread, gathers hit L2), then scans 1024 vertices
// (4/thread) against the 256-face tile.
// key = (monotone_map(bits of (0.5||b||^2 - a.b)) << 32) | face_idx
// argmin(key) == argmin(d2) with lowest-index tie-break (matches jnp.argmin).
// ---------------------------------------------------------------------------
__global__ __launch_bounds__(TB) void k_nn(
    const float* __restrict__ cloth_prev,
    const float* __restrict__ obs_prev,
    const int* __restrict__ faces,
    unsigned long long* __restrict__ out,   // [NC][N_CLOTH] partials, or keys[N] (atomic)
    int atomicMode)
{
    __shared__ float4 tile[CHUNK];
    const int t = threadIdx.x;
    const int bv = blockIdx.x;      // vertex block 0..VBLK-1
    const int c  = blockIdx.y;      // face chunk   0..NC-1
    const int fbase = c * CHUNK;

    // build this chunk's prev-center tile (one face per thread)
    {
        int f = fbase + t;
        int i0 = faces[3 * f + 0];
        int i1 = faces[3 * f + 1];
        int i2 = faces[3 * f + 2];
        float ax = obs_prev[3 * i0 + 0], ay = obs_prev[3 * i0 + 1], az = obs_prev[3 * i0 + 2];
        float bx = obs_prev[3 * i1 + 0], by = obs_prev[3 * i1 + 1], bz = obs_prev[3 * i1 + 2];
        float cx = obs_prev[3 * i2 + 0], cy = obs_prev[3 * i2 + 1], cz = obs_prev[3 * i2 + 2];
        float pcx = (ax + bx + cx) * (1.0f / 3.0f);
        float pcy = (ay + by + cy) * (1.0f / 3.0f);
        float pcz = (az + bz + cz) * (1.0f / 3.0f);
        float b2h = 0.5f * (pcx * pcx + pcy * pcy + pcz * pcz);
        tile[t] = make_float4(pcx, pcy, pcz, b2h);
    }

    float vx[VPT], vy[VPT], vz[VPT], best[VPT];
    int bidx[VPT];
#pragma unroll
    for (int j = 0; j < VPT; ++j) {
        int n = bv * (TB * VPT) + j * TB + t;
        vx[j] = cloth_prev[3 * n + 0];
        vy[j] = cloth_prev[3 * n + 1];
        vz[j] = cloth_prev[3 * n + 2];
        best[j] = 3.4e38f;
        bidx[j] = 0;
    }
    __syncthreads();

#pragma unroll 4
    for (int f = 0; f < CHUNK; ++f) {
        float4 b = tile[f];
#pragma unroll
        for (int j = 0; j < VPT; ++j) {
            float s = fmaf(-vx[j], b.x, b.w);
            s = fmaf(-vy[j], b.y, s);
            s = fmaf(-vz[j], b.z, s);
            bool lt = s < best[j];
            bidx[j] = lt ? f : bidx[j];
            best[j] = fminf(s, best[j]);
        }
    }

#pragma unroll
    for (int j = 0; j < VPT; ++j) {
        int n = bv * (TB * VPT) + j * TB + t;
        unsigned int ub = __float_as_uint(best[j]);
        ub = (ub & 0x80000000u) ? ~ub : (ub | 0x80000000u);  // monotone map (s can be <0)
        unsigned long long key =
            ((unsigned long long)ub << 32) | (unsigned int)(fbase + bidx[j]);
        if (atomicMode) atomicMin(&out[n], key);
        else out[(size_t)c * N_CLOTH + n] = key;
    }
}

// ---------------------------------------------------------------------------
// K2: reduce chunk keys per vertex, compute chosen face's current center +
// unit normal on the fly, cubic penalty, block-sum -> lossPartial[block]
// ---------------------------------------------------------------------------
__global__ __launch_bounds__(256) void k_loss(
    const float* __restrict__ cloth_pred,
    const float* __restrict__ obs_pos,
    const int* __restrict__ faces,
    const unsigned long long* __restrict__ partials,  // [C][N] (C=1 for atomic path)
    int C,
    float* __restrict__ lossPartial)
{
    const int t = threadIdx.x;
    const int n = blockIdx.x * blockDim.x + t;

    unsigned long long k = partials[n];
    for (int c = 1; c < C; ++c) {
        unsigned long long v = partials[(size_t)c * N_CLOTH + n];
        k = (v < k) ? v : k;
    }
    int idx = (int)(unsigned int)(k & 0xFFFFFFFFull);

    int i0 = faces[3 * idx + 0];
    int i1 = faces[3 * idx + 1];
    int i2 = faces[3 * idx + 2];
    float ux = obs_pos[3 * i0 + 0], uy = obs_pos[3 * i0 + 1], uz = obs_pos[3 * i0 + 2];
    float vx = obs_pos[3 * i1 + 0], vy = obs_pos[3 * i1 + 1], vz = obs_pos[3 * i1 + 2];
    float wx = obs_pos[3 * i2 + 0], wy = obs_pos[3 * i2 + 1], wz = obs_pos[3 * i2 + 2];

    float fpx = (ux + vx + wx) * (1.0f / 3.0f);
    float fpy = (uy + vy + wy) * (1.0f / 3.0f);
    float fpz = (uz + vz + wz) * (1.0f / 3.0f);

    float e1x = vx - ux, e1y = vy - uy, e1z = vz - uz;
    float e2x = wx - ux, e2y = wy - uy, e2z = wz - uz;
    float nx = e1y * e2z - e1z * e2y;
    float ny = e1z * e2x - e1x * e2z;
    float nz = e1x * e2y - e1y * e2x;
    float nrm = sqrtf(nx * nx + ny * ny + nz * nz);
    float inv = 1.0f / fmaxf(nrm, 1e-12f);

    float px = cloth_pred[3 * n + 0];
    float py = cloth_pred[3 * n + 1];
    float pz = cloth_pred[3 * n + 2];
    float d = (px - fpx) * nx * inv + (py - fpy) * ny * inv + (pz - fpz) * nz * inv;
    float tt = fmaxf(1e-3f - d, 0.0f);
    float val = tt * tt * tt;

    __shared__ float red[256];
    red[t] = val;
    __syncthreads();
    for (int s = 128; s > 0; s >>= 1) {
        if (t < s) red[t] += red[t + s];
        __syncthreads();
    }
    if (t == 0) lossPartial[blockIdx.x] = red[0];
}

// ---------------------------------------------------------------------------
// K3: final 64-partial sum * weight(iteration) -> d_out[0]
// ---------------------------------------------------------------------------
__global__ __launch_bounds__(64) void k_final(
    const float* __restrict__ lossPartial,
    const int* __restrict__ iteration,
    float* __restrict__ out)
{
    int t = threadIdx.x;
    float v = lossPartial[t];
#pragma unroll
    for (int o = 32; o > 0; o >>= 1) v += __shfl_down(v, o);
    if (t == 0) {
        int it = iteration[0];
        float itf = (float)(it - 50000);
        itf = fmaxf(itf, 0.0f);
        float prog = fminf(itf * (1.0f / 100000.0f), 1.0f);
        float w = 1.0f + (5000.0f - 1.0f) * prog;
        out[0] = v * w;
    }
}

extern "C" void kernel_launch(void* const* d_in, const int* in_sizes, int n_in,
                              void* d_out, int out_size, void* d_ws, size_t ws_size,
                              hipStream_t stream) {
    const float* obs_pos    = (const float*)d_in[0];
    const float* obs_prev   = (const float*)d_in[1];
    const int*   faces      = (const int*)d_in[2];
    const float* cloth_prev = (const float*)d_in[3];
    const float* cloth_pred = (const float*)d_in[4];
    const int*   iteration  = (const int*)d_in[5];
    float* out = (float*)d_out;

    char* ws = (char*)d_ws;
    float* lossPartial           = (float*)(ws);                      // 1 KB (64 used)
    unsigned long long* keys     = (unsigned long long*)(ws + 1024);  // 128 KB
    unsigned long long* partials = (unsigned long long*)(ws + 1024 + 131072);  // 8 MB

    const size_t need_partials =
        1024ull + 131072ull + (size_t)NC * N_CLOTH * sizeof(unsigned long long);
    const bool useAtomic = ws_size < need_partials;

    if (useAtomic) {
        hipMemsetAsync(keys, 0xFF, N_CLOTH * sizeof(unsigned long long), stream);
        k_nn<<<dim3(VBLK, NC), TB, 0, stream>>>(cloth_prev, obs_prev, faces, keys, 1);
        k_loss<<<N_CLOTH / 256, 256, 0, stream>>>(cloth_pred, obs_pos, faces,
                                                  keys, 1, lossPartial);
    } else {
        k_nn<<<dim3(VBLK, NC), TB, 0, stream>>>(cloth_prev, obs_prev, faces, partials, 0);
        k_loss<<<N_CLOTH / 256, 256, 0, stream>>>(cloth_pred, obs_pos, faces,
                                                  partials, NC, lossPartial);
    }
    k_final<<<1, 64, 0, stream>>>(lossPartial, iteration, out);
}

// Round 3
// 66.995 us; speedup vs baseline: 1.0484x; 1.0484x over previous
//
#include <hip/hip_runtime.h>
#include <hip/hip_bf16.h>
#include <stdint.h>

#define N_CLOTH     16384
#define N_OBS_VERTS 8192
#define N_OBS_FACES 16384

#define CHUNK 256                        // faces per chunk (SGPR-tiled, 4KB in L2)
#define NC    (N_OBS_FACES / CHUNK)      // 64 chunks
#define VPT   4                          // vertices per thread
#define TB    256                        // threads per block
#define VBLK  (N_CLOTH / (TB * VPT))     // 16 vertex-blocks -> grid 16x64 = 1024 blocks

// ---------------------------------------------------------------------------
// K0: prev-face centers -> faceA[f] = (cx, cy, cz, 0.5*||c||^2)
// ---------------------------------------------------------------------------
__global__ __launch_bounds__(256) void k_faces(
    const float* __restrict__ obs_prev, const int* __restrict__ faces,
    float4* __restrict__ faceA)
{
    int f = blockIdx.x * blockDim.x + threadIdx.x;
    if (f >= N_OBS_FACES) return;
    int i0 = faces[3 * f + 0];
    int i1 = faces[3 * f + 1];
    int i2 = faces[3 * f + 2];
    float ax = obs_prev[3 * i0 + 0], ay = obs_prev[3 * i0 + 1], az = obs_prev[3 * i0 + 2];
    float bx = obs_prev[3 * i1 + 0], by = obs_prev[3 * i1 + 1], bz = obs_prev[3 * i1 + 2];
    float cx = obs_prev[3 * i2 + 0], cy = obs_prev[3 * i2 + 1], cz = obs_prev[3 * i2 + 2];
    float pcx = (ax + bx + cx) * (1.0f / 3.0f);
    float pcy = (ay + by + cy) * (1.0f / 3.0f);
    float pcz = (az + bz + cz) * (1.0f / 3.0f);
    float b2h = 0.5f * (pcx * pcx + pcy * pcy + pcz * pcz);
    faceA[f] = make_float4(pcx, pcy, pcz, b2h);
}

// ---------------------------------------------------------------------------
// K1: NN scan. Face tile read through UNIFORM addresses -> compiler emits
// s_load_dwordx16 into SGPRs (SMEM pipe); hot loop is pure VALU, no LDS.
// key = (monotone_map(bits of (0.5||b||^2 - a.b)) << 32) | face_idx
// argmin(key) == argmin(d2) with lowest-index tie-break (matches jnp.argmin).
// ---------------------------------------------------------------------------
#define PROC(b, ff)                                                  \
    {                                                                \
        _Pragma("unroll")                                            \
        for (int j = 0; j < VPT; ++j) {                              \
            float s = fmaf(-vx[j], (b).x, (b).w);                    \
            s = fmaf(-vy[j], (b).y, s);                              \
            s = fmaf(-vz[j], (b).z, s);                              \
            bool lt = s < best[j];                                   \
            bidx[j] = lt ? (ff) : bidx[j];                           \
            best[j] = fminf(s, best[j]);                             \
        }                                                            \
    }

__global__ __launch_bounds__(TB) void k_nn(
    const float* __restrict__ cloth_prev,
    const float4* __restrict__ faceA,
    unsigned long long* __restrict__ out,   // [NC][N_CLOTH] partials, or keys[N] (atomic)
    int atomicMode)
{
    const int t = threadIdx.x;
    const int bv = blockIdx.x;      // vertex block 0..VBLK-1
    const int c  = blockIdx.y;      // face chunk   0..NC-1
    const int fbase = c * CHUNK;

    float vx[VPT], vy[VPT], vz[VPT], best[VPT];
    int bidx[VPT];
#pragma unroll
    for (int j = 0; j < VPT; ++j) {
        int n = bv * (TB * VPT) + j * TB + t;
        vx[j] = cloth_prev[3 * n + 0];
        vy[j] = cloth_prev[3 * n + 1];
        vz[j] = cloth_prev[3 * n + 2];
        best[j] = 3.4e38f;
        bidx[j] = 0;
    }

    // g is wave-uniform -> faceA[fbase+g+k] are uniform loads -> SMEM (s_load)
#pragma unroll 2
    for (int g = 0; g < CHUNK; g += 4) {
        float4 b0 = faceA[fbase + g + 0];
        float4 b1 = faceA[fbase + g + 1];
        float4 b2 = faceA[fbase + g + 2];
        float4 b3 = faceA[fbase + g + 3];
        PROC(b0, g + 0)
        PROC(b1, g + 1)
        PROC(b2, g + 2)
        PROC(b3, g + 3)
    }

#pragma unroll
    for (int j = 0; j < VPT; ++j) {
        int n = bv * (TB * VPT) + j * TB + t;
        unsigned int ub = __float_as_uint(best[j]);
        ub = (ub & 0x80000000u) ? ~ub : (ub | 0x80000000u);  // monotone map (s can be <0)
        unsigned long long key =
            ((unsigned long long)ub << 32) | (unsigned int)(fbase + bidx[j]);
        if (atomicMode) atomicMin(&out[n], key);
        else out[(size_t)c * N_CLOTH + n] = key;
    }
}

// ---------------------------------------------------------------------------
// K2: reduce chunk keys per vertex, compute chosen face's current center +
// unit normal on the fly, cubic penalty, block-sum, weight, atomicAdd -> out
// ---------------------------------------------------------------------------
__global__ __launch_bounds__(256) void k_loss(
    const float* __restrict__ cloth_pred,
    const float* __restrict__ obs_pos,
    const int* __restrict__ faces,
    const unsigned long long* __restrict__ partials,  // [C][N] (C=1 for atomic path)
    int C,
    const int* __restrict__ iteration,
    float* __restrict__ out)
{
    const int t = threadIdx.x;
    const int n = blockIdx.x * blockDim.x + t;

    unsigned long long k = partials[n];
#pragma unroll 8
    for (int c = 1; c < C; ++c) {
        unsigned long long v = partials[(size_t)c * N_CLOTH + n];
        k = (v < k) ? v : k;
    }
    int idx = (int)(unsigned int)(k & 0xFFFFFFFFull);

    int i0 = faces[3 * idx + 0];
    int i1 = faces[3 * idx + 1];
    int i2 = faces[3 * idx + 2];
    float ux = obs_pos[3 * i0 + 0], uy = obs_pos[3 * i0 + 1], uz = obs_pos[3 * i0 + 2];
    float vx = obs_pos[3 * i1 + 0], vy = obs_pos[3 * i1 + 1], vz = obs_pos[3 * i1 + 2];
    float wx = obs_pos[3 * i2 + 0], wy = obs_pos[3 * i2 + 1], wz = obs_pos[3 * i2 + 2];

    float fpx = (ux + vx + wx) * (1.0f / 3.0f);
    float fpy = (uy + vy + wy) * (1.0f / 3.0f);
    float fpz = (uz + vz + wz) * (1.0f / 3.0f);

    float e1x = vx - ux, e1y = vy - uy, e1z = vz - uz;
    float e2x = wx - ux, e2y = wy - uy, e2z = wz - uz;
    float nx = e1y * e2z - e1z * e2y;
    float ny = e1z * e2x - e1x * e2z;
    float nz = e1x * e2y - e1y * e2x;
    float nrm = sqrtf(nx * nx + ny * ny + nz * nz);
    float inv = 1.0f / fmaxf(nrm, 1e-12f);

    float px = cloth_pred[3 * n + 0];
    float py = cloth_pred[3 * n + 1];
    float pz = cloth_pred[3 * n + 2];
    float d = (px - fpx) * nx * inv + (py - fpy) * ny * inv + (pz - fpz) * nz * inv;
    float tt = fmaxf(1e-3f - d, 0.0f);
    float val = tt * tt * tt;

    __shared__ float red[256];
    red[t] = val;
    __syncthreads();
    for (int s = 128; s > 0; s >>= 1) {
        if (t < s) red[t] += red[t + s];
        __syncthreads();
    }
    if (t == 0) {
        int it = iteration[0];
        float itf = fmaxf((float)(it - 50000), 0.0f);
        float prog = fminf(itf * (1.0f / 100000.0f), 1.0f);
        float w = 1.0f + (5000.0f - 1.0f) * prog;
        atomicAdd(out, red[0] * w);
    }
}

extern "C" void kernel_launch(void* const* d_in, const int* in_sizes, int n_in,
                              void* d_out, int out_size, void* d_ws, size_t ws_size,
                              hipStream_t stream) {
    const float* obs_pos    = (const float*)d_in[0];
    const float* obs_prev   = (const float*)d_in[1];
    const int*   faces      = (const int*)d_in[2];
    const float* cloth_prev = (const float*)d_in[3];
    const float* cloth_pred = (const float*)d_in[4];
    const int*   iteration  = (const int*)d_in[5];
    float* out = (float*)d_out;

    char* ws = (char*)d_ws;
    float4* faceA                = (float4*)(ws);                     // 256 KB
    unsigned long long* keys     = (unsigned long long*)(ws + 262144);        // 128 KB
    unsigned long long* partials = (unsigned long long*)(ws + 262144 + 131072); // 8 MB

    const size_t need_partials =
        262144ull + 131072ull + (size_t)NC * N_CLOTH * sizeof(unsigned long long);
    const bool useAtomic = ws_size < need_partials;

    hipMemsetAsync(out, 0, sizeof(float), stream);
    k_faces<<<N_OBS_FACES / 256, 256, 0, stream>>>(obs_prev, faces, faceA);

    if (useAtomic) {
        hipMemsetAsync(keys, 0xFF, N_CLOTH * sizeof(unsigned long long), stream);
        k_nn<<<dim3(VBLK, NC), TB, 0, stream>>>(cloth_prev, faceA, keys, 1);
        k_loss<<<N_CLOTH / 256, 256, 0, stream>>>(cloth_pred, obs_pos, faces,
                                                  keys, 1, iteration, out);
    } else {
        k_nn<<<dim3(VBLK, NC), TB, 0, stream>>>(cloth_prev, faceA, partials, 0);
        k_loss<<<N_CLOTH / 256, 256, 0, stream>>>(cloth_pred, obs_pos, faces,
                                                  partials, NC, iteration, out);
    }
}

// Round 4
// 66.312 us; speedup vs baseline: 1.0592x; 1.0103x over previous
//
#include <hip/hip_runtime.h>
#include <hip/hip_bf16.h>
#include <stdint.h>

#define N_CLOTH     16384
#define N_OBS_VERTS 8192
#define N_OBS_FACES 16384

#define CHUNK 128                        // faces per chunk (LDS tile = 2KB)
#define NC    (N_OBS_FACES / CHUNK)      // 128 chunks
#define VPT   8                          // vertices per thread
#define TB    256                        // threads per block
#define VBLK  (N_CLOTH / (TB * VPT))     // 8 vertex-blocks -> grid 8x128 = 1024 blocks

// ---------------------------------------------------------------------------
// K1 (fused tile build + NN): each block builds its chunk's 128 prev-face
// centers in LDS (threads 0..127, gathers hit L2), then scans 2048 vertices
// (8/thread) against the tile. LDS reads are wave-uniform broadcasts (free),
// operands are VGPRs -> inner loop is exactly 6 VALU/pair:
//   3 fma + v_cmp + v_cndmask + v_min.
// key = (monotone_map(bits of (0.5||b||^2 - a.b)) << 32) | face_idx
// argmin(key) == argmin(d2) with lowest-index tie-break (matches jnp.argmin).
// ---------------------------------------------------------------------------
__global__ __launch_bounds__(TB) void k_nn(
    const float* __restrict__ cloth_prev,
    const float* __restrict__ obs_prev,
    const int* __restrict__ faces,
    unsigned long long* __restrict__ out,   // [NC][N_CLOTH] partials, or keys[N] (atomic)
    int atomicMode)
{
    __shared__ float4 tile[CHUNK];
    const int t = threadIdx.x;
    const int bv = blockIdx.x;      // vertex block 0..VBLK-1
    const int c  = blockIdx.y;      // face chunk   0..NC-1
    const int fbase = c * CHUNK;

    // build this chunk's prev-center tile (threads 0..CHUNK-1, one face each)
    if (t < CHUNK) {
        int f = fbase + t;
        int i0 = faces[3 * f + 0];
        int i1 = faces[3 * f + 1];
        int i2 = faces[3 * f + 2];
        float ax = obs_prev[3 * i0 + 0], ay = obs_prev[3 * i0 + 1], az = obs_prev[3 * i0 + 2];
        float bx = obs_prev[3 * i1 + 0], by = obs_prev[3 * i1 + 1], bz = obs_prev[3 * i1 + 2];
        float cx = obs_prev[3 * i2 + 0], cy = obs_prev[3 * i2 + 1], cz = obs_prev[3 * i2 + 2];
        float pcx = (ax + bx + cx) * (1.0f / 3.0f);
        float pcy = (ay + by + cy) * (1.0f / 3.0f);
        float pcz = (az + bz + cz) * (1.0f / 3.0f);
        float b2h = 0.5f * (pcx * pcx + pcy * pcy + pcz * pcz);
        tile[t] = make_float4(pcx, pcy, pcz, b2h);
    }

    float vx[VPT], vy[VPT], vz[VPT], best[VPT];
    int bidx[VPT];
#pragma unroll
    for (int j = 0; j < VPT; ++j) {
        int n = bv * (TB * VPT) + j * TB + t;
        vx[j] = cloth_prev[3 * n + 0];
        vy[j] = cloth_prev[3 * n + 1];
        vz[j] = cloth_prev[3 * n + 2];
        best[j] = 3.4e38f;
        bidx[j] = 0;
    }
    __syncthreads();

#pragma unroll 4
    for (int f = 0; f < CHUNK; ++f) {
        float4 b = tile[f];
#pragma unroll
        for (int j = 0; j < VPT; ++j) {
            float s = fmaf(-vx[j], b.x, b.w);
            s = fmaf(-vy[j], b.y, s);
            s = fmaf(-vz[j], b.z, s);
            bool lt = s < best[j];
            bidx[j] = lt ? f : bidx[j];
            best[j] = fminf(s, best[j]);
        }
    }

#pragma unroll
    for (int j = 0; j < VPT; ++j) {
        int n = bv * (TB * VPT) + j * TB + t;
        unsigned int ub = __float_as_uint(best[j]);
        ub = (ub & 0x80000000u) ? ~ub : (ub | 0x80000000u);  // monotone map (s can be <0)
        unsigned long long key =
            ((unsigned long long)ub << 32) | (unsigned int)(fbase + bidx[j]);
        if (atomicMode) atomicMin(&out[n], key);
        else out[(size_t)c * N_CLOTH + n] = key;
    }
}

// ---------------------------------------------------------------------------
// K2: reduce chunk keys per vertex, compute chosen face's current center +
// unit normal on the fly, cubic penalty, block-sum, weight, atomicAdd -> out
// ---------------------------------------------------------------------------
__global__ __launch_bounds__(256) void k_loss(
    const float* __restrict__ cloth_pred,
    const float* __restrict__ obs_pos,
    const int* __restrict__ faces,
    const unsigned long long* __restrict__ partials,  // [C][N] (C=1 for atomic path)
    int C,
    const int* __restrict__ iteration,
    float* __restrict__ out)
{
    const int t = threadIdx.x;
    const int n = blockIdx.x * blockDim.x + t;

    unsigned long long k = partials[n];
#pragma unroll 8
    for (int c = 1; c < C; ++c) {
        unsigned long long v = partials[(size_t)c * N_CLOTH + n];
        k = (v < k) ? v : k;
    }
    int idx = (int)(unsigned int)(k & 0xFFFFFFFFull);

    int i0 = faces[3 * idx + 0];
    int i1 = faces[3 * idx + 1];
    int i2 = faces[3 * idx + 2];
    float ux = obs_pos[3 * i0 + 0], uy = obs_pos[3 * i0 + 1], uz = obs_pos[3 * i0 + 2];
    float vx = obs_pos[3 * i1 + 0], vy = obs_pos[3 * i1 + 1], vz = obs_pos[3 * i1 + 2];
    float wx = obs_pos[3 * i2 + 0], wy = obs_pos[3 * i2 + 1], wz = obs_pos[3 * i2 + 2];

    float fpx = (ux + vx + wx) * (1.0f / 3.0f);
    float fpy = (uy + vy + wy) * (1.0f / 3.0f);
    float fpz = (uz + vz + wz) * (1.0f / 3.0f);

    float e1x = vx - ux, e1y = vy - uy, e1z = vz - uz;
    float e2x = wx - ux, e2y = wy - uy, e2z = wz - uz;
    float nx = e1y * e2z - e1z * e2y;
    float ny = e1z * e2x - e1x * e2z;
    float nz = e1x * e2y - e1y * e2x;
    float nrm = sqrtf(nx * nx + ny * ny + nz * nz);
    float inv = 1.0f / fmaxf(nrm, 1e-12f);

    float px = cloth_pred[3 * n + 0];
    float py = cloth_pred[3 * n + 1];
    float pz = cloth_pred[3 * n + 2];
    float d = (px - fpx) * nx * inv + (py - fpy) * ny * inv + (pz - fpz) * nz * inv;
    float tt = fmaxf(1e-3f - d, 0.0f);
    float val = tt * tt * tt;

    __shared__ float red[256];
    red[t] = val;
    __syncthreads();
    for (int s = 128; s > 0; s >>= 1) {
        if (t < s) red[t] += red[t + s];
        __syncthreads();
    }
    if (t == 0) {
        int it = iteration[0];
        float itf = fmaxf((float)(it - 50000), 0.0f);
        float prog = fminf(itf * (1.0f / 100000.0f), 1.0f);
        float w = 1.0f + (5000.0f - 1.0f) * prog;
        atomicAdd(out, red[0] * w);
    }
}

extern "C" void kernel_launch(void* const* d_in, const int* in_sizes, int n_in,
                              void* d_out, int out_size, void* d_ws, size_t ws_size,
                              hipStream_t stream) {
    const float* obs_pos    = (const float*)d_in[0];
    const float* obs_prev   = (const float*)d_in[1];
    const int*   faces      = (const int*)d_in[2];
    const float* cloth_prev = (const float*)d_in[3];
    const float* cloth_pred = (const float*)d_in[4];
    const int*   iteration  = (const int*)d_in[5];
    float* out = (float*)d_out;

    char* ws = (char*)d_ws;
    unsigned long long* keys     = (unsigned long long*)(ws);                 // 128 KB
    unsigned long long* partials = (unsigned long long*)(ws + 131072);        // 16.8 MB

    const size_t need_partials =
        131072ull + (size_t)NC * N_CLOTH * sizeof(unsigned long long);
    const bool useAtomic = ws_size < need_partials;

    hipMemsetAsync(out, 0, sizeof(float), stream);

    if (useAtomic) {
        hipMemsetAsync(keys, 0xFF, N_CLOTH * sizeof(unsigned long long), stream);
        k_nn<<<dim3(VBLK, NC), TB, 0, stream>>>(cloth_prev, obs_prev, faces, keys, 1);
        k_loss<<<N_CLOTH / 256, 256, 0, stream>>>(cloth_pred, obs_pos, faces,
                                                  keys, 1, iteration, out);
    } else {
        k_nn<<<dim3(VBLK, NC), TB, 0, stream>>>(cloth_prev, obs_prev, faces, partials, 0);
        k_loss<<<N_CLOTH / 256, 256, 0, stream>>>(cloth_pred, obs_pos, faces,
                                                  partials, NC, iteration, out);
    }
}

// Round 5
// 53.282 us; speedup vs baseline: 1.3182x; 1.2446x over previous
//
#include <hip/hip_runtime.h>
#include <hip/hip_bf16.h>
#include <stdint.h>

#define N_CLOTH     16384
#define N_OBS_VERTS 8192
#define N_OBS_FACES 16384

#define CHUNK 128                        // faces per chunk (LDS tile = 2KB)
#define NGRP  (CHUNK / 4)                // 32 groups of 4 faces
#define NC    (N_OBS_FACES / CHUNK)      // 128 chunks
#define VPT   8                          // vertices per thread
#define TB    256                        // threads per block
#define VBLK  (N_CLOTH / (TB * VPT))     // 8 vertex-blocks -> grid 8x128 = 1024 blocks

// ---------------------------------------------------------------------------
// K1 (fused tile build + NN, grouped-min inner loop):
// Main loop processes 4 faces/group: 12 fma + min3/min tree + strict-< group
// tracking = 17 VALU / 4 pairs (4.25/pair vs 6). Face-level argmin recovered
// in an epilogue by bit-identical recompute of the winning group's 4 faces +
// lowest-index equality scan. Matches jnp.argmin tie-break exactly:
//  - strict < across groups keeps the earliest group on ties
//  - descending equality scan keeps the lowest face within the group
// key = (monotone_map(bits of (0.5||b||^2 - a.b)) << 32) | face_idx
// ---------------------------------------------------------------------------
__global__ __launch_bounds__(TB) void k_nn(
    const float* __restrict__ cloth_prev,
    const float* __restrict__ obs_prev,
    const int* __restrict__ faces,
    unsigned long long* __restrict__ out,   // [NC][N_CLOTH] partials, or keys[N] (atomic)
    int atomicMode)
{
    __shared__ float4 tile[CHUNK];
    const int t = threadIdx.x;
    const int bv = blockIdx.x;      // vertex block 0..VBLK-1
    const int c  = blockIdx.y;      // face chunk   0..NC-1
    const int fbase = c * CHUNK;

    // build this chunk's prev-center tile (threads 0..CHUNK-1, one face each)
    if (t < CHUNK) {
        int f = fbase + t;
        int i0 = faces[3 * f + 0];
        int i1 = faces[3 * f + 1];
        int i2 = faces[3 * f + 2];
        float ax = obs_prev[3 * i0 + 0], ay = obs_prev[3 * i0 + 1], az = obs_prev[3 * i0 + 2];
        float bx = obs_prev[3 * i1 + 0], by = obs_prev[3 * i1 + 1], bz = obs_prev[3 * i1 + 2];
        float cx = obs_prev[3 * i2 + 0], cy = obs_prev[3 * i2 + 1], cz = obs_prev[3 * i2 + 2];
        float pcx = (ax + bx + cx) * (1.0f / 3.0f);
        float pcy = (ay + by + cy) * (1.0f / 3.0f);
        float pcz = (az + bz + cz) * (1.0f / 3.0f);
        float b2h = 0.5f * (pcx * pcx + pcy * pcy + pcz * pcz);
        tile[t] = make_float4(pcx, pcy, pcz, b2h);
    }

    float vx[VPT], vy[VPT], vz[VPT], best[VPT];
    int gbest[VPT];
#pragma unroll
    for (int j = 0; j < VPT; ++j) {
        int n = bv * (TB * VPT) + j * TB + t;
        vx[j] = cloth_prev[3 * n + 0];
        vy[j] = cloth_prev[3 * n + 1];
        vz[j] = cloth_prev[3 * n + 2];
        best[j] = 3.4e38f;
        gbest[j] = 0;
    }
    __syncthreads();

#pragma unroll 2
    for (int gi = 0; gi < NGRP; ++gi) {
        float4 b0 = tile[4 * gi + 0];
        float4 b1 = tile[4 * gi + 1];
        float4 b2 = tile[4 * gi + 2];
        float4 b3 = tile[4 * gi + 3];
#pragma unroll
        for (int j = 0; j < VPT; ++j) {
            float s0 = fmaf(-vx[j], b0.x, b0.w);
            s0 = fmaf(-vy[j], b0.y, s0);
            s0 = fmaf(-vz[j], b0.z, s0);
            float s1 = fmaf(-vx[j], b1.x, b1.w);
            s1 = fmaf(-vy[j], b1.y, s1);
            s1 = fmaf(-vz[j], b1.z, s1);
            float s2 = fmaf(-vx[j], b2.x, b2.w);
            s2 = fmaf(-vy[j], b2.y, s2);
            s2 = fmaf(-vz[j], b2.z, s2);
            float s3 = fmaf(-vx[j], b3.x, b3.w);
            s3 = fmaf(-vy[j], b3.y, s3);
            s3 = fmaf(-vz[j], b3.z, s3);
            // min tree -> v_min3_f32 + v_min_f32
            float m = fminf(fminf(fminf(s0, s1), s2), s3);
            bool lt = m < best[j];
            gbest[j] = lt ? gi : gbest[j];
            best[j] = fminf(m, best[j]);
        }
    }

    // epilogue: recover face index within winning group (bit-identical recompute)
#pragma unroll
    for (int j = 0; j < VPT; ++j) {
        int gb = gbest[j];
        float4 B0 = tile[4 * gb + 0];
        float4 B1 = tile[4 * gb + 1];
        float4 B2 = tile[4 * gb + 2];
        float4 B3 = tile[4 * gb + 3];
        float r0 = fmaf(-vx[j], B0.x, B0.w);
        r0 = fmaf(-vy[j], B0.y, r0);
        r0 = fmaf(-vz[j], B0.z, r0);
        float r1 = fmaf(-vx[j], B1.x, B1.w);
        r1 = fmaf(-vy[j], B1.y, r1);
        r1 = fmaf(-vz[j], B1.z, r1);
        float r2 = fmaf(-vx[j], B2.x, B2.w);
        r2 = fmaf(-vy[j], B2.y, r2);
        r2 = fmaf(-vz[j], B2.z, r2);
        float r3 = fmaf(-vx[j], B3.x, B3.w);
        r3 = fmaf(-vy[j], B3.y, r3);
        r3 = fmaf(-vz[j], B3.z, r3);
        float bb = best[j];
        int idx = 4 * gb + 3;
        idx = (r2 == bb) ? 4 * gb + 2 : idx;   // descending -> lowest wins
        idx = (r1 == bb) ? 4 * gb + 1 : idx;
        idx = (r0 == bb) ? 4 * gb + 0 : idx;

        int n = bv * (TB * VPT) + j * TB + t;
        unsigned int ub = __float_as_uint(bb);
        ub = (ub & 0x80000000u) ? ~ub : (ub | 0x80000000u);  // monotone map (s can be <0)
        unsigned long long key =
            ((unsigned long long)ub << 32) | (unsigned int)(fbase + idx);
        if (atomicMode) atomicMin(&out[n], key);
        else out[(size_t)c * N_CLOTH + n] = key;
    }
}

// ---------------------------------------------------------------------------
// K2: reduce chunk keys per vertex, compute chosen face's current center +
// unit normal on the fly, cubic penalty, block-sum, weight, atomicAdd -> out
// ---------------------------------------------------------------------------
__global__ __launch_bounds__(256) void k_loss(
    const float* __restrict__ cloth_pred,
    const float* __restrict__ obs_pos,
    const int* __restrict__ faces,
    const unsigned long long* __restrict__ partials,  // [C][N] (C=1 for atomic path)
    int C,
    const int* __restrict__ iteration,
    float* __restrict__ out)
{
    const int t = threadIdx.x;
    const int n = blockIdx.x * blockDim.x + t;

    unsigned long long k = partials[n];
#pragma unroll 8
    for (int c = 1; c < C; ++c) {
        unsigned long long v = partials[(size_t)c * N_CLOTH + n];
        k = (v < k) ? v : k;
    }
    int idx = (int)(unsigned int)(k & 0xFFFFFFFFull);

    int i0 = faces[3 * idx + 0];
    int i1 = faces[3 * idx + 1];
    int i2 = faces[3 * idx + 2];
    float ux = obs_pos[3 * i0 + 0], uy = obs_pos[3 * i0 + 1], uz = obs_pos[3 * i0 + 2];
    float vx = obs_pos[3 * i1 + 0], vy = obs_pos[3 * i1 + 1], vz = obs_pos[3 * i1 + 2];
    float wx = obs_pos[3 * i2 + 0], wy = obs_pos[3 * i2 + 1], wz = obs_pos[3 * i2 + 2];

    float fpx = (ux + vx + wx) * (1.0f / 3.0f);
    float fpy = (uy + vy + wy) * (1.0f / 3.0f);
    float fpz = (uz + vz + wz) * (1.0f / 3.0f);

    float e1x = vx - ux, e1y = vy - uy, e1z = vz - uz;
    float e2x = wx - ux, e2y = wy - uy, e2z = wz - uz;
    float nx = e1y * e2z - e1z * e2y;
    float ny = e1z * e2x - e1x * e2z;
    float nz = e1x * e2y - e1y * e2x;
    float nrm = sqrtf(nx * nx + ny * ny + nz * nz);
    float inv = 1.0f / fmaxf(nrm, 1e-12f);

    float px = cloth_pred[3 * n + 0];
    float py = cloth_pred[3 * n + 1];
    float pz = cloth_pred[3 * n + 2];
    float d = (px - fpx) * nx * inv + (py - fpy) * ny * inv + (pz - fpz) * nz * inv;
    float tt = fmaxf(1e-3f - d, 0.0f);
    float val = tt * tt * tt;

    __shared__ float red[256];
    red[t] = val;
    __syncthreads();
    for (int s = 128; s > 0; s >>= 1) {
        if (t < s) red[t] += red[t + s];
        __syncthreads();
    }
    if (t == 0) {
        int it = iteration[0];
        float itf = fmaxf((float)(it - 50000), 0.0f);
        float prog = fminf(itf * (1.0f / 100000.0f), 1.0f);
        float w = 1.0f + (5000.0f - 1.0f) * prog;
        atomicAdd(out, red[0] * w);
    }
}

extern "C" void kernel_launch(void* const* d_in, const int* in_sizes, int n_in,
                              void* d_out, int out_size, void* d_ws, size_t ws_size,
                              hipStream_t stream) {
    const float* obs_pos    = (const float*)d_in[0];
    const float* obs_prev   = (const float*)d_in[1];
    const int*   faces      = (const int*)d_in[2];
    const float* cloth_prev = (const float*)d_in[3];
    const float* cloth_pred = (const float*)d_in[4];
    const int*   iteration  = (const int*)d_in[5];
    float* out = (float*)d_out;

    char* ws = (char*)d_ws;
    unsigned long long* keys     = (unsigned long long*)(ws);                 // 128 KB
    unsigned long long* partials = (unsigned long long*)(ws + 131072);        // 16.8 MB

    const size_t need_partials =
        131072ull + (size_t)NC * N_CLOTH * sizeof(unsigned long long);
    const bool useAtomic = ws_size < need_partials;

    hipMemsetAsync(out, 0, sizeof(float), stream);

    if (useAtomic) {
        hipMemsetAsync(keys, 0xFF, N_CLOTH * sizeof(unsigned long long), stream);
        k_nn<<<dim3(VBLK, NC), TB, 0, stream>>>(cloth_prev, obs_prev, faces, keys, 1);
        k_loss<<<N_CLOTH / 256, 256, 0, stream>>>(cloth_pred, obs_pos, faces,
                                                  keys, 1, iteration, out);
    } else {
        k_nn<<<dim3(VBLK, NC), TB, 0, stream>>>(cloth_prev, obs_prev, faces, partials, 0);
        k_loss<<<N_CLOTH / 256, 256, 0, stream>>>(cloth_pred, obs_pos, faces,
                                                  partials, NC, iteration, out);
    }
}